// Round 1
// baseline (1789.274 us; speedup 1.0000x reference)
//
#include <hip/hip_runtime.h>
#include <hip/hip_bf16.h>

// Problem constants (Llama4TextExperts: 8 experts, pre-sorted tokens)
#define NE 8
#define HD 2048   // hidden
#define FD 4096   // expert_dim (per gate/up half)
#define TT 1024   // tokens per expert (8192 / 8)

// Tile config
#define BM 128
#define BN 64
#define BK 32
#define LDA 40    // padded leading dim (bf16 elems): 80B rows, 16B-aligned

using bf16 = __hip_bfloat16;
typedef __attribute__((ext_vector_type(8))) short bf16x8;
typedef __attribute__((ext_vector_type(4))) float f32x4;

__device__ __forceinline__ bf16 f2b(float x) { return __float2bfloat16(x); }

// ---------------------------------------------------------------------------
// GEMM1 + SwiGLU: inter[e][t][f] = up * silu(gate)
//   X  : (NE*TT, HD) fp32       A, row-major
//   W1 : (NE, HD, 2*FD) fp32    B, row-major (gate cols [0,FD), up cols [FD,2FD))
//   inter: (NE, TT, FD) bf16    output
// ---------------------------------------------------------------------------
__global__ __launch_bounds__(256, 2) void gemm1_swiglu(const float* __restrict__ X,
                                                       const float* __restrict__ W1,
                                                       bf16* __restrict__ inter) {
  __shared__ bf16 As[BM][LDA];
  __shared__ bf16 Bg[BN][LDA];
  __shared__ bf16 Bu[BN][LDA];

  const int e  = blockIdx.z;
  const int m0 = blockIdx.y * BM;
  const int n0 = blockIdx.x * BN;

  const float* Xe = X + (size_t)e * TT * HD + (size_t)m0 * HD;
  const float* We = W1 + (size_t)e * HD * (2 * FD);

  const int tid  = threadIdx.x;
  const int lane = tid & 63;
  const int wave = tid >> 6;
  const int wm   = (wave >> 1) * 64;  // wave row offset in tile
  const int wn   = (wave & 1) * 32;   // wave col offset in tile
  const int lrow = lane & 15;
  const int quad = lane >> 4;

  f32x4 accg[4][2] = {};
  f32x4 accu[4][2] = {};

  // staging thread mapping
  const int aRow = tid >> 3;        // 0..31 (A: 8 thr/row, 4 fp32 each)
  const int aCol = (tid & 7) * 4;   // 0..28
  const int bK   = tid >> 4;        // 0..15 (B: 16 thr/k-row, 4 fp32 each)
  const int bN   = (tid & 15) * 4;  // 0..60

  for (int k0 = 0; k0 < HD; k0 += BK) {
    // ---- stage A tile (BM x BK), fp32 -> bf16, row-major ----
#pragma unroll
    for (int p = 0; p < 4; ++p) {
      const int r = p * 32 + aRow;
      const float4 v = *reinterpret_cast<const float4*>(Xe + (size_t)r * HD + k0 + aCol);
      union { bf16 h[4]; uint2 u; } pk;
      pk.h[0] = f2b(v.x); pk.h[1] = f2b(v.y); pk.h[2] = f2b(v.z); pk.h[3] = f2b(v.w);
      *reinterpret_cast<uint2*>(&As[r][aCol]) = pk.u;
    }
    // ---- stage B gate & up tiles (BK x BN), transposed into LDS [n][k] ----
#pragma unroll
    for (int p = 0; p < 2; ++p) {
      const int k = p * 16 + bK;
      const float* rowp = We + (size_t)(k0 + k) * (2 * FD) + n0 + bN;
      const float4 vg = *reinterpret_cast<const float4*>(rowp);
      const float4 vu = *reinterpret_cast<const float4*>(rowp + FD);
      Bg[bN + 0][k] = f2b(vg.x); Bg[bN + 1][k] = f2b(vg.y);
      Bg[bN + 2][k] = f2b(vg.z); Bg[bN + 3][k] = f2b(vg.w);
      Bu[bN + 0][k] = f2b(vu.x); Bu[bN + 1][k] = f2b(vu.y);
      Bu[bN + 2][k] = f2b(vu.z); Bu[bN + 3][k] = f2b(vu.w);
    }
    __syncthreads();

    // ---- fragments + MFMA ----
    bf16x8 a[4], bg[2], bu[2];
#pragma unroll
    for (int i = 0; i < 4; ++i)
      a[i] = *reinterpret_cast<const bf16x8*>(&As[wm + i * 16 + lrow][quad * 8]);
#pragma unroll
    for (int j = 0; j < 2; ++j) {
      bg[j] = *reinterpret_cast<const bf16x8*>(&Bg[wn + j * 16 + lrow][quad * 8]);
      bu[j] = *reinterpret_cast<const bf16x8*>(&Bu[wn + j * 16 + lrow][quad * 8]);
    }
#pragma unroll
    for (int i = 0; i < 4; ++i) {
#pragma unroll
      for (int j = 0; j < 2; ++j) {
        accg[i][j] = __builtin_amdgcn_mfma_f32_16x16x32_bf16(a[i], bg[j], accg[i][j], 0, 0, 0);
        accu[i][j] = __builtin_amdgcn_mfma_f32_16x16x32_bf16(a[i], bu[j], accu[i][j], 0, 0, 0);
      }
    }
    __syncthreads();
  }

  // ---- epilogue: SwiGLU, write bf16 inter ----
  bf16* Ie = inter + (size_t)e * TT * FD;
#pragma unroll
  for (int i = 0; i < 4; ++i) {
#pragma unroll
    for (int j = 0; j < 2; ++j) {
      const int row = m0 + wm + i * 16 + quad * 4;
      const int col = n0 + wn + j * 16 + lrow;
#pragma unroll
      for (int r = 0; r < 4; ++r) {
        const float g = accg[i][j][r];
        const float u = accu[i][j][r];
        const float s = g / (1.0f + __expf(-g));  // silu(g)
        Ie[(size_t)(row + r) * FD + col] = f2b(u * s);
      }
    }
  }
}

// ---------------------------------------------------------------------------
// GEMM2: out[e][t][h] = inter[e][t][:] @ W2[e][:,h]
//   inter: (NE, TT, FD) bf16   A, row-major
//   W2   : (NE, FD, HD) fp32   B, row-major
//   out  : (NE*TT, HD) fp32
// ---------------------------------------------------------------------------
__global__ __launch_bounds__(256, 2) void gemm2(const bf16* __restrict__ inter,
                                                const float* __restrict__ W2,
                                                float* __restrict__ out) {
  __shared__ bf16 As[BM][LDA];
  __shared__ bf16 Bs[BN][LDA];

  const int e  = blockIdx.z;
  const int m0 = blockIdx.y * BM;
  const int n0 = blockIdx.x * BN;

  const bf16* Ie = inter + (size_t)e * TT * FD + (size_t)m0 * FD;
  const float* We = W2 + (size_t)e * FD * HD;
  float* Oe = out + (size_t)e * TT * HD + (size_t)m0 * HD;

  const int tid  = threadIdx.x;
  const int lane = tid & 63;
  const int wave = tid >> 6;
  const int wm   = (wave >> 1) * 64;
  const int wn   = (wave & 1) * 32;
  const int lrow = lane & 15;
  const int quad = lane >> 4;

  f32x4 acc[4][2] = {};

  const int aRow = tid >> 2;        // 0..63 (A: 4 thr/row, 8 bf16 each)
  const int aK8  = (tid & 3) * 8;   // 0..24
  const int bK   = tid >> 4;        // 0..15
  const int bN   = (tid & 15) * 4;  // 0..60

  for (int k0 = 0; k0 < FD; k0 += BK) {
    // ---- stage A tile (bf16 direct copy, 16B vectors) ----
#pragma unroll
    for (int p = 0; p < 2; ++p) {
      const int r = p * 64 + aRow;
      const uint4 v = *reinterpret_cast<const uint4*>(Ie + (size_t)r * FD + k0 + aK8);
      *reinterpret_cast<uint4*>(&As[r][aK8]) = v;
    }
    // ---- stage B tile (fp32 -> bf16, transposed [n][k]) ----
#pragma unroll
    for (int p = 0; p < 2; ++p) {
      const int k = p * 16 + bK;
      const float4 v = *reinterpret_cast<const float4*>(We + (size_t)(k0 + k) * HD + n0 + bN);
      Bs[bN + 0][k] = f2b(v.x); Bs[bN + 1][k] = f2b(v.y);
      Bs[bN + 2][k] = f2b(v.z); Bs[bN + 3][k] = f2b(v.w);
    }
    __syncthreads();

    bf16x8 a[4], b[2];
#pragma unroll
    for (int i = 0; i < 4; ++i)
      a[i] = *reinterpret_cast<const bf16x8*>(&As[wm + i * 16 + lrow][quad * 8]);
#pragma unroll
    for (int j = 0; j < 2; ++j)
      b[j] = *reinterpret_cast<const bf16x8*>(&Bs[wn + j * 16 + lrow][quad * 8]);
#pragma unroll
    for (int i = 0; i < 4; ++i) {
#pragma unroll
      for (int j = 0; j < 2; ++j) {
        acc[i][j] = __builtin_amdgcn_mfma_f32_16x16x32_bf16(a[i], b[j], acc[i][j], 0, 0, 0);
      }
    }
    __syncthreads();
  }

  // ---- epilogue: fp32 out ----
#pragma unroll
  for (int i = 0; i < 4; ++i) {
#pragma unroll
    for (int j = 0; j < 2; ++j) {
      const int row = wm + i * 16 + quad * 4;
      const int col = n0 + wn + j * 16 + lrow;
#pragma unroll
      for (int r = 0; r < 4; ++r) {
        Oe[(size_t)(row + r) * HD + col] = acc[i][j][r];
      }
    }
  }
}

// ---------------------------------------------------------------------------
extern "C" void kernel_launch(void* const* d_in, const int* in_sizes, int n_in,
                              void* d_out, int out_size, void* d_ws, size_t ws_size,
                              hipStream_t stream) {
  const float* X  = (const float*)d_in[0];   // hidden_states (8192, 2048) fp32
  const float* W1 = (const float*)d_in[1];   // gate_up_proj (8, 2048, 8192) fp32
  const float* W2 = (const float*)d_in[2];   // down_proj (8, 4096, 2048) fp32
  float* out = (float*)d_out;                // (8192, 2048) fp32
  bf16* inter = (bf16*)d_ws;                 // (8, 1024, 4096) bf16 = 64 MB scratch

  dim3 blk(256, 1, 1);
  dim3 g1(FD / BN, TT / BM, NE);  // 64 x 8 x 8 = 4096 blocks
  hipLaunchKernelGGL(gemm1_swiglu, g1, blk, 0, stream, X, W1, inter);
  dim3 g2(HD / BN, TT / BM, NE);  // 32 x 8 x 8 = 2048 blocks
  hipLaunchKernelGGL(gemm2, g2, blk, 0, stream, inter, W2, out);
}